// Round 2
// baseline (371.825 us; speedup 1.0000x reference)
//
#include <hip/hip_runtime.h>

// SubGraphAvgPool: out[b,g,d] = mean(h[b,g,d], h[b,4g+1,d], h[b,4g+2,d], h[b,4g+3,d], h[b,4g+4,d])
// B=16, N=8193, D=512, m=4 -> G=2048. fp32 in, fp32 out (per reference dtypes).
//
// One thread per float4 (16B). Row = 512 fp32 = 128 float4 chunks; 2 waves per row.
// All 5 loads + 1 store are fully coalesced 16B/lane accesses.

#define B_ 16
#define N_ 8193
#define D_ 512
#define G_ 2048

__global__ __launch_bounds__(256) void subgraph_avgpool_kernel(
        const float* __restrict__ h,
        float* __restrict__ out) {
    const int tid = blockIdx.x * blockDim.x + threadIdx.x;
    const int c  = tid & 127;          // which float4 chunk within the row (128 per row)
    const int bg = tid >> 7;           // output row index (b*G + g)
    const int g  = bg & (G_ - 1);
    const int b  = bg >> 11;           // G_ = 2048

    const size_t d = (size_t)c * 4;
    const size_t hb = (size_t)b * ((size_t)N_ * D_);
    const float* pr = h + hb + (size_t)g * D_ + d;            // root row g
    const float* pm = h + hb + ((size_t)4 * g + 1) * D_ + d;  // member rows 4g+1..4g+4

    const float4 v0 = *(const float4*)pr;
    const float4 v1 = *(const float4*)(pm);
    const float4 v2 = *(const float4*)(pm + D_);
    const float4 v3 = *(const float4*)(pm + 2 * D_);
    const float4 v4 = *(const float4*)(pm + 3 * D_);

    const float s = 0.2f;
    float4 r;
    r.x = (v0.x + v1.x + v2.x + v3.x + v4.x) * s;
    r.y = (v0.y + v1.y + v2.y + v3.y + v4.y) * s;
    r.z = (v0.z + v1.z + v2.z + v3.z + v4.z) * s;
    r.w = (v0.w + v1.w + v2.w + v3.w + v4.w) * s;

    *(float4*)(out + (size_t)bg * D_ + d) = r;
}

extern "C" void kernel_launch(void* const* d_in, const int* in_sizes, int n_in,
                              void* d_out, int out_size, void* d_ws, size_t ws_size,
                              hipStream_t stream) {
    const float* h = (const float*)d_in[0];
    float* out = (float*)d_out;
    // total threads = B*G*(D/4) = 16*2048*128 = 4,194,304 -> 16384 blocks of 256
    const int total = B_ * G_ * (D_ / 4);
    const int block = 256;
    const int grid = total / block;
    subgraph_avgpool_kernel<<<grid, block, 0, stream>>>(h, out);
}